// Round 16
// baseline (289.371 us; speedup 1.0000x reference)
//
#include <hip/hip_runtime.h>
#include <math.h>

constexpr float R_MAX   = 5.0f;
constexpr float INV_R   = 0.2f;                     // 1/R_MAX
constexpr float PI_F    = 3.14159265358979323846f;
constexpr float C0      = 0.632455532033675866f;    // sqrt(2/R_MAX)
constexpr float INV_AVG = 1.0f / 16.0f;             // 1/AVG_NEIGH
constexpr int   TBL     = 4096;                     // table resolution
constexpr int   SCHUNK  = 512;                      // scan chunk per block

__device__ __forceinline__ float sigm(float x) { return 1.0f / (1.0f + __expf(-x)); }

// f32 -> bf16 (round-to-nearest-even)
__device__ __forceinline__ unsigned f2bf(float x) {
    unsigned u = __float_as_uint(x);
    u += 0x7fffu + ((u >> 16) & 1u);
    return u >> 16;
}
__device__ __forceinline__ void store_bf_row(unsigned short* dst, const float* v) {
    uint4* o = (uint4*)dst;
#pragma unroll
    for (int w = 0; w < 4; w++) {
        uint4 t;
        t.x = f2bf(v[8*w+0]) | (f2bf(v[8*w+1]) << 16);
        t.y = f2bf(v[8*w+2]) | (f2bf(v[8*w+3]) << 16);
        t.z = f2bf(v[8*w+4]) | (f2bf(v[8*w+5]) << 16);
        t.w = f2bf(v[8*w+6]) | (f2bf(v[8*w+7]) << 16);
        o[w] = t;
    }
}
__device__ __forceinline__ void load_bf_row(const unsigned short* src, float* v) {
    const uint4* p = (const uint4*)src;
#pragma unroll
    for (int w = 0; w < 4; w++) {
        uint4 t = p[w];
        v[8*w+0] = __uint_as_float(t.x << 16);
        v[8*w+1] = __uint_as_float(t.x & 0xffff0000u);
        v[8*w+2] = __uint_as_float(t.y << 16);
        v[8*w+3] = __uint_as_float(t.y & 0xffff0000u);
        v[8*w+4] = __uint_as_float(t.z << 16);
        v[8*w+5] = __uint_as_float(t.z & 0xffff0000u);
        v[8*w+6] = __uint_as_float(t.w << 16);
        v[8*w+7] = __uint_as_float(t.w & 0xffff0000u);
    }
}

// ef plus d(ef)/dL (exact, used only in the table path)
__device__ __forceinline__ void radial_ef_d(float u, float invL, float* ef, float* dd) {
    float u2 = u * u, u4 = u2 * u2, u5 = u4 * u;
    float fc  = 1.f - 21.f * u5 + 35.f * u5 * u - 15.f * u5 * u2;
    float om  = 1.f - u;
    float fcp = -105.f * u4 * om * om;   // dfc/du
    float sp, cp;
    sincosf(PI_F * u, &sp, &cp);
    float twoc = 2.f * cp;
    float a = C0 * invL;
    float s_nm1 = 0.f, s_n = sp, c_nm1 = 1.f, c_n = cp;
#pragma unroll
    for (int n = 1; n <= 8; n++) {
        ef[n - 1] = a * s_n * fc;
        dd[n - 1] = a * fc * ((float)n * PI_F * INV_R * c_n - s_n * invL)
                  + a * s_n * fcp * INV_R;
        if (n < 8) {
            float sn2 = twoc * s_n - s_nm1; s_nm1 = s_n; s_n = sn2;
            float cn2 = twoc * c_n - c_nm1; c_nm1 = c_n; c_n = cn2;
        }
    }
}

// Fused setup: blocks [0,nbt) build tables, [nbt,nbt+nbn) embed nodes,
// [nbt+nbn, ...) build edge histograms + urec (1 edge/thread — the ILP-2
// variant of this path crashed in round 15; reverted).
// NOTE: hist_r/hist_s are zeroed by a hipMemsetAsync BEFORE this kernel —
// zeroing them in the embed path raced with build-path atomics (block
// execution order within one launch is undefined).
__global__ __launch_bounds__(256) void k_setup(
    const float* __restrict__ W1a, const float* __restrict__ W2a,
    const float* __restrict__ W1b, const float* __restrict__ W2b,
    float* __restrict__ twa, float* __restrict__ dta,
    float* __restrict__ twb, float* __restrict__ dtb,
    float* __restrict__ total,
    const float* __restrict__ attrs, const float* __restrict__ ae,
    const float* __restrict__ Wemb, float* __restrict__ h,
    unsigned short* __restrict__ hA1_bf, float* __restrict__ e0,
    float* __restrict__ A1, float* __restrict__ forces, int N,
    const float* __restrict__ pos, const float* __restrict__ shifts,
    const int* __restrict__ ei, int E,
    int* __restrict__ hist_r, int* __restrict__ hist_s,
    float4* __restrict__ urec,
    int nbt, int nbn)
{
    int b = blockIdx.x;
    if (b < nbt) {
        // ---------------- table path ----------------
        if (b == 0 && threadIdx.x < 32) total[threadIdx.x] = 0.f;
        int gid = b * 256 + threadIdx.x;
        if (gid >= (TBL + 1) * 16) return;
        int cg = gid & 7;
        int l  = (gid >> 3) & 1;
        int t  = gid >> 4;
        float u = fmaxf((float)t / (float)TBL, 1e-4f);
        float L = u * R_MAX;
        float invL = 1.f / L;
        float ef[8], dd[8], efu[8];
        radial_ef_d(u, invL, ef, dd);
#pragma unroll
        for (int k = 0; k < 8; k++) efu[k] = dd[k] * R_MAX;
        const float* W1 = l ? W1b : W1a;
        const float* W2 = l ? W2b : W2a;
        float*     tw_o = l ? twb : twa;
        float*     dt_o = l ? dtb : dta;
        float tw[4] = {0.f, 0.f, 0.f, 0.f};
        float dt[4] = {0.f, 0.f, 0.f, 0.f};
        for (int j = 0; j < 64; j++) {
            float s1 = 0.f, du = 0.f;
#pragma unroll
            for (int k = 0; k < 8; k++) {
                float w = W1[k * 64 + j];
                s1 += ef[k] * w; du += efu[k] * w;
            }
            float sg  = sigm(s1);
            float act = s1 * sg;
            float dj  = sg * (1.f + s1 * (1.f - sg)) * du;
            const float* w2 = W2 + j * 96 + cg * 4;
#pragma unroll
            for (int q = 0; q < 4; q++) {
                tw[q] += act * w2[q];
                dt[q] += dj * w2[q];
            }
        }
#pragma unroll
        for (int q = 0; q < 4; q++) {
            tw_o[(size_t)t * 32 + cg * 4 + q] = tw[q];
            dt_o[(size_t)t * 32 + cg * 4 + q] = dt[q];
        }
    } else if (b < nbt + nbn) {
        // ---------------- embed path ----------------
        int i = (b - nbt) * 256 + threadIdx.x;
        if (i >= N) return;
        float a[10];
#pragma unroll
        for (int k = 0; k < 10; k++) a[k] = attrs[i * 10 + k];
        float e = 0.f;
#pragma unroll
        for (int k = 0; k < 10; k++) e += a[k] * ae[k];
        e0[i] = e;
        float v[32];
#pragma unroll
        for (int c = 0; c < 32; c++) {
            float t = 0.f;
#pragma unroll
            for (int k = 0; k < 10; k++) t += a[k] * Wemb[k * 32 + c];
            v[c] = t;
            h[i * 32 + c] = t;
            A1[i * 32 + c] = 0.f;
        }
        store_bf_row(hA1_bf + (size_t)i * 64, v);   // h half of packed row
        forces[3*i+0] = 0.f; forces[3*i+1] = 0.f; forces[3*i+2] = 0.f;
    } else {
        // ---------------- build path (1 edge/thread) ----------------
        int e = (b - nbt - nbn) * 256 + threadIdx.x;
        if (e >= E) return;
        int s = ei[e], r = ei[E + e];
        float vx = pos[3*r+0] - pos[3*s+0] + shifts[3*e+0];
        float vy = pos[3*r+1] - pos[3*s+1] + shifts[3*e+1];
        float vz = pos[3*r+2] - pos[3*s+2] + shifts[3*e+2];
        float ss2 = vx*vx + vy*vy + vz*vz;
        float L = sqrtf(fmaxf(ss2, 1e-12f));
        if (L * INV_R < 1.f) {
            atomicAdd(&hist_r[r], 1);
            atomicAdd(&hist_s[s], 1);
            urec[e] = make_float4(vx, vy, vz,
                      __uint_as_float(((unsigned)s << 16) | (unsigned)r));
        } else {
            urec[e] = make_float4(0.f, 0.f, 0.f, __uint_as_float(0xFFFFFFFFu));
        }
    }
}

// hierarchical scan stage A: per-block chunk sums (both hists in one grid)
__global__ __launch_bounds__(256) void k_scan_a(
    const int* __restrict__ hist_r, const int* __restrict__ hist_s,
    int n, int nb, int* __restrict__ part)
{
    __shared__ int red[256];
    int b = blockIdx.x;
    const int* hist = (b < nb) ? hist_r : hist_s;
    int cb = (b < nb) ? b : b - nb;
    int base = cb * SCHUNK;
    int t = threadIdx.x;
    int i0 = base + 2 * t, i1 = i0 + 1;
    int sum = 0;
    if (i0 < n) sum += hist[i0];
    if (i1 < n) sum += hist[i1];
    red[t] = sum;
    __syncthreads();
    for (int off = 128; off > 0; off >>= 1) {
        if (t < off) red[t] += red[t + off];
        __syncthreads();
    }
    if (t == 0) part[b] = red[0];
}

// stage B: exclusive scan of the block sums (in LDS, one block); writes cnt
__global__ __launch_bounds__(256) void k_scan_b(
    const int* __restrict__ part, int nb, int* __restrict__ bbase,
    int* __restrict__ cnt)
{
    __shared__ int buf[512];   // 2*nb <= 512
    int t = threadIdx.x;
    for (int k = t; k < 2 * nb; k += 256) buf[k] = part[k];
    __syncthreads();
    if (t < 2) {
        int base = t * nb;
        int run = 0;
        for (int k = 0; k < nb; k++) {
            int v = buf[base + k];
            buf[base + k] = run;
            run += v;
        }
        if (t == 0) *cnt = run;   // total active
    }
    __syncthreads();
    for (int k = t; k < 2 * nb; k += 256) bbase[k] = buf[k];
}

// stage C: per-chunk exclusive scan + block base -> cursor arrays
__global__ __launch_bounds__(256) void k_scan_c(
    const int* __restrict__ hist_r, const int* __restrict__ hist_s,
    int n, int nb, const int* __restrict__ bbase,
    int* __restrict__ cur_r, int* __restrict__ cur_s)
{
    __shared__ int sc[256];
    int b = blockIdx.x;
    const int* hist = (b < nb) ? hist_r : hist_s;
    int*       cur  = (b < nb) ? cur_r : cur_s;
    int cb = (b < nb) ? b : b - nb;
    int base = cb * SCHUNK;
    int t = threadIdx.x;
    int i0 = base + 2 * t, i1 = i0 + 1;
    int e0 = (i0 < n) ? hist[i0] : 0;
    int e1 = (i1 < n) ? hist[i1] : 0;
    int ts = e0 + e1;
    sc[t] = ts;
    __syncthreads();
    for (int off = 1; off < 256; off <<= 1) {
        int v = (t >= off) ? sc[t - off] : 0;
        __syncthreads();
        sc[t] += v;
        __syncthreads();
    }
    int excl = sc[t] - ts + bbase[b];
    if (i0 < n) cur[i0] = excl;
    if (i1 < n) cur[i1] = excl + e0;
}

// receiver-side scatter only: 1 atomic chain per edge, 2 edges per thread
__global__ __launch_bounds__(256) void k_sort_r(
    const float4* __restrict__ urec, int E,
    int* __restrict__ cur_r, float4* __restrict__ rrec,
    int* __restrict__ rp_of_e)
{
    int base = blockIdx.x * 512;
    int t = threadIdx.x;
    int e0 = base + t, e1 = base + 256 + t;
    float4 u0, u1;
    unsigned p0 = 0xFFFFFFFFu, p1 = 0xFFFFFFFFu;
    if (e0 < E) { u0 = urec[e0]; p0 = __float_as_uint(u0.w); }
    if (e1 < E) { u1 = urec[e1]; p1 = __float_as_uint(u1.w); }
    int rp0 = -1, rp1 = -1;
    if (p0 != 0xFFFFFFFFu) rp0 = atomicAdd(&cur_r[p0 & 0xffffu], 1);
    if (p1 != 0xFFFFFFFFu) rp1 = atomicAdd(&cur_r[p1 & 0xffffu], 1);
    if (rp0 >= 0) { rrec[rp0] = u0; rp_of_e[e0] = rp0; }
    if (rp1 >= 0) { rrec[rp1] = u1; rp_of_e[e1] = rp1; }
}

// mlp pass 1 (blocks [0,nb_g)) FUSED with the sender-side scatter
__global__ __launch_bounds__(256) void k_mlp1_sorts(
    const float4* __restrict__ rec, const int* __restrict__ cnt,
    const float* __restrict__ tw_tbl, const unsigned short* __restrict__ feat,
    float* __restrict__ acc,
    const float4* __restrict__ urec, int E, int* __restrict__ cur_s,
    float4* __restrict__ srec, int* __restrict__ map_sr,
    const int* __restrict__ rp_of_e, int nb_g)
{
    __shared__ float m_lds[256][33];
    __shared__ int   dst_lds[256];

    int b = blockIdx.x;
    int tid = threadIdx.x;

    if (b >= nb_g) {
        // ------------- sender-side scatter (sort_s), 512 edges/block -------------
        int base = (b - nb_g) * 512;
        int e0 = base + tid, e1 = base + 256 + tid;
        float4 u0, u1;
        unsigned p0 = 0xFFFFFFFFu, p1 = 0xFFFFFFFFu;
        if (e0 < E) { u0 = urec[e0]; p0 = __float_as_uint(u0.w); }
        if (e1 < E) { u1 = urec[e1]; p1 = __float_as_uint(u1.w); }
        int sp0 = -1, sp1 = -1;
        if (p0 != 0xFFFFFFFFu) sp0 = atomicAdd(&cur_s[p0 >> 16], 1);
        if (p1 != 0xFFFFFFFFu) sp1 = atomicAdd(&cur_s[p1 >> 16], 1);
        if (sp0 >= 0) {
            unsigned r = p0 & 0xffffu, s = p0 >> 16;
            srec[sp0] = make_float4(u0.x, u0.y, u0.z,
                        __uint_as_float((r << 16) | s));
            map_sr[sp0] = rp_of_e[e0];
        }
        if (sp1 >= 0) {
            unsigned r = p1 & 0xffffu, s = p1 >> 16;
            srec[sp1] = make_float4(u1.x, u1.y, u1.z,
                        __uint_as_float((r << 16) | s));
            map_sr[sp1] = rp_of_e[e1];
        }
        return;
    }

    // ------------- mlp pass 1 over rrec -------------
    int na = *cnt;
    int stride = nb_g * 256;
    for (int base = b * 256; base < na; base += stride) {
        int i = base + tid;
        int dst = -1;
        if (i < na) {
            float4 rv = rec[i];
            unsigned pk = __float_as_uint(rv.w);
            int gn = pk >> 16;
            dst = (int)(pk & 0xffffu);
            float ss2 = rv.x * rv.x + rv.y * rv.y + rv.z * rv.z;
            float L = sqrtf(fmaxf(ss2, 1e-12f));
            float x = fminf(L * (INV_R * (float)TBL), (float)TBL - 1e-3f);
            int   i0 = (int)x;
            float f  = x - (float)i0;

            float fbuf[32];
            load_bf_row(feat + (size_t)gn * 64, fbuf);

            const float4* r0 = (const float4*)(tw_tbl + (size_t)i0 * 32);
            const float4* r1 = r0 + 8;
#pragma unroll
            for (int q = 0; q < 8; q++) {
                float4 a = r0[q], bb = r1[q];
                m_lds[tid][4 * q + 0] = fbuf[4*q+0] * (a.x + f * (bb.x - a.x));
                m_lds[tid][4 * q + 1] = fbuf[4*q+1] * (a.y + f * (bb.y - a.y));
                m_lds[tid][4 * q + 2] = fbuf[4*q+2] * (a.z + f * (bb.z - a.z));
                m_lds[tid][4 * q + 3] = fbuf[4*q+3] * (a.w + f * (bb.w - a.w));
            }
        }
        dst_lds[tid] = dst;
        __syncthreads();

        int grp = tid >> 5;
        int c   = tid & 31;
        int b32 = grp * 32;
        int cur = -1; float run = 0.f;
        for (int k = 0; k < 32; k++) {
            int d = dst_lds[b32 + k];
            if (d != cur) {
                if (cur >= 0) unsafeAtomicAdd(&acc[(size_t)cur * 32 + c], run);
                cur = d;
                run = (d >= 0) ? m_lds[b32 + k][c] : 0.f;
            } else if (d >= 0) {
                run += m_lds[b32 + k][c];
            }
        }
        if (cur >= 0) unsafeAtomicAdd(&acc[(size_t)cur * 32 + c], run);
        __syncthreads();
    }
}

// table-driven edge MLP (pass 2 over rrec): m = bf16feat[gather]*lerp(tw)
__global__ __launch_bounds__(256) void k_edge_mlp_t(
    const float4* __restrict__ rec, const int* __restrict__ cnt,
    const float* __restrict__ tw_tbl, const unsigned short* __restrict__ feat,
    int fstride, float* __restrict__ acc)
{
    __shared__ float m_lds[256][33];
    __shared__ int   dst_lds[256];

    int na = *cnt;
    int tid = threadIdx.x;
    int stride = gridDim.x * 256;

    for (int base = blockIdx.x * 256; base < na; base += stride) {
        int i = base + tid;
        int dst = -1;
        if (i < na) {
            float4 rv = rec[i];
            unsigned pk = __float_as_uint(rv.w);
            int gn = pk >> 16;
            dst = (int)(pk & 0xffffu);
            float ss2 = rv.x * rv.x + rv.y * rv.y + rv.z * rv.z;
            float L = sqrtf(fmaxf(ss2, 1e-12f));
            float x = fminf(L * (INV_R * (float)TBL), (float)TBL - 1e-3f);
            int   i0 = (int)x;
            float f  = x - (float)i0;

            float fbuf[32];
            load_bf_row(feat + (size_t)gn * fstride, fbuf);

            const float4* r0 = (const float4*)(tw_tbl + (size_t)i0 * 32);
            const float4* r1 = r0 + 8;
#pragma unroll
            for (int q = 0; q < 8; q++) {
                float4 a = r0[q], b = r1[q];
                m_lds[tid][4 * q + 0] = fbuf[4*q+0] * (a.x + f * (b.x - a.x));
                m_lds[tid][4 * q + 1] = fbuf[4*q+1] * (a.y + f * (b.y - a.y));
                m_lds[tid][4 * q + 2] = fbuf[4*q+2] * (a.z + f * (b.z - a.z));
                m_lds[tid][4 * q + 3] = fbuf[4*q+3] * (a.w + f * (b.w - a.w));
            }
        }
        dst_lds[tid] = dst;
        __syncthreads();

        int grp = tid >> 5;
        int c   = tid & 31;
        int b32 = grp * 32;
        int cur = -1; float run = 0.f;
        for (int k = 0; k < 32; k++) {
            int d = dst_lds[b32 + k];
            if (d != cur) {
                if (cur >= 0) unsafeAtomicAdd(&acc[(size_t)cur * 32 + c], run);
                cur = d;
                run = (d >= 0) ? m_lds[b32 + k][c] : 0.f;
            } else if (d >= 0) {
                run += m_lds[b32 + k][c];
            }
        }
        if (cur >= 0) unsafeAtomicAdd(&acc[(size_t)cur * 32 + c], run);
        __syncthreads();
    }
}

// node1: finalize A1, write bf16 A1-half of packed row, zero A2g2 row
__global__ __launch_bounds__(256) void k_node1(
    const float* __restrict__ h, float* __restrict__ A1,
    unsigned short* __restrict__ hA1_bf,
    const float* __restrict__ Wr1, float* __restrict__ e1,
    float* __restrict__ A2g2, int N)
{
    int i = blockIdx.x * blockDim.x + threadIdx.x;
    if (i >= N) return;
    float dot = 0.f;
    float v[32];
#pragma unroll
    for (int c = 0; c < 32; c++) {
        float t = A1[i * 32 + c] * INV_AVG + h[i * 32 + c];
        v[c] = t;
        A1[i * 32 + c] = t;
        A2g2[i * 32 + c] = 0.f;
        dot += t * Wr1[c];
    }
    e1[i] = dot;
    store_bf_row(hA1_bf + (size_t)i * 64 + 32, v);   // A1 half of packed row
}

// node2: A2 -> energies + g2 (in place) + bf16 mirror; zeroes g1 row
__global__ __launch_bounds__(256) void k_node2(
    float* __restrict__ A2g2, unsigned short* __restrict__ g2_bf,
    const float* __restrict__ A1,
    const float* __restrict__ Wm1, const float* __restrict__ Wm2,
    const float* __restrict__ e0, const float* __restrict__ e1,
    float* __restrict__ node_e, float* __restrict__ total,
    float* __restrict__ g1, const int* __restrict__ batch, int N)
{
    __shared__ float bins[32];
    if (threadIdx.x < 32) bins[threadIdx.x] = 0.f;
    __syncthreads();
    int i = blockIdx.x * blockDim.x + threadIdx.x;
    if (i < N) {
        float A2[32];
#pragma unroll
        for (int c = 0; c < 32; c++) {
            A2[c] = A2g2[i * 32 + c] * INV_AVG + A1[i * 32 + c];
            g1[i * 32 + c] = 0.f;
        }
        float z[16];
#pragma unroll
        for (int k = 0; k < 16; k++) {
            float v = 0.f;
#pragma unroll
            for (int c = 0; c < 32; c++) v += A2[c] * Wm1[c * 16 + k];
            z[k] = v;
        }
        float e2 = 0.f;
        float wk[16];
#pragma unroll
        for (int k = 0; k < 16; k++) {
            float sg = sigm(z[k]);
            float m2 = Wm2[k];
            e2 += z[k] * sg * m2;
            wk[k] = m2 * sg * (1.f + z[k] * (1.f - sg));  // Wm2 * silu'(z)
        }
        float g2v[32];
#pragma unroll
        for (int c = 0; c < 32; c++) {
            float v = 0.f;
#pragma unroll
            for (int k = 0; k < 16; k++) v += Wm1[c * 16 + k] * wk[k];
            g2v[c] = v;
            A2g2[i * 32 + c] = v;                          // g2 in place
        }
        store_bf_row(g2_bf + (size_t)i * 32, g2v);
        float ne = e0[i] + e1[i] + e2;
        node_e[i] = ne;
        atomicAdd(&bins[batch[i]], ne);
    }
    __syncthreads();
    if (threadIdx.x < 32) unsafeAtomicAdd(&total[threadIdx.x], bins[threadIdx.x]);
}

// mlp pass 3 FUSED with force branch-b (over srec).
__global__ __launch_bounds__(256) void k_mlp3fb(
    const float4* __restrict__ rec, const int* __restrict__ cnt,
    const float* __restrict__ tw_tbl, const float* __restrict__ dt_tbl,
    const unsigned short* __restrict__ g2_bf,
    const unsigned short* __restrict__ hA1_bf,
    const int* __restrict__ map_sr,
    float* __restrict__ g1acc, float* __restrict__ dotb_buf)
{
    __shared__ float m_lds[256][33];
    __shared__ int   dst_lds[256];

    int na = *cnt;
    int tid = threadIdx.x;
    int stride = gridDim.x * 256;

    for (int base = blockIdx.x * 256; base < na; base += stride) {
        int i = base + tid;
        int dst = -1;
        if (i < na) {
            float4 rv = rec[i];
            unsigned pk = __float_as_uint(rv.w);
            int r = (int)(pk >> 16);       // gather node (receiver)
            dst = (int)(pk & 0xffffu);     // scatter node (sender)
            float ss2 = rv.x * rv.x + rv.y * rv.y + rv.z * rv.z;
            float L = sqrtf(fmaxf(ss2, 1e-12f));
            float x = fminf(L * (INV_R * (float)TBL), (float)TBL - 1e-3f);
            int   i0 = (int)x;
            float f  = x - (float)i0;

            float gb[32], ab[32];
            load_bf_row(g2_bf + (size_t)r * 32, gb);            // random 64B
            load_bf_row(hA1_bf + (size_t)dst * 64 + 32, ab);    // sorted, L1-hot

            const float4* r0 = (const float4*)(tw_tbl + (size_t)i0 * 32);
            const float4* r1 = r0 + 8;
            const float4* d0 = (const float4*)(dt_tbl + (size_t)i0 * 32);
            const float4* d1 = d0 + 8;
            float dotb = 0.f;
#pragma unroll
            for (int q = 0; q < 8; q++) {
                float4 a = r0[q], b = r1[q], da = d0[q], db = d1[q];
                float t0 = a.x + f * (b.x - a.x);
                float t1 = a.y + f * (b.y - a.y);
                float t2 = a.z + f * (b.z - a.z);
                float t3 = a.w + f * (b.w - a.w);
                m_lds[tid][4*q+0] = gb[4*q+0] * t0;
                m_lds[tid][4*q+1] = gb[4*q+1] * t1;
                m_lds[tid][4*q+2] = gb[4*q+2] * t2;
                m_lds[tid][4*q+3] = gb[4*q+3] * t3;
                dotb += gb[4*q+0] * ab[4*q+0] * (da.x + f * (db.x - da.x))
                      + gb[4*q+1] * ab[4*q+1] * (da.y + f * (db.y - da.y))
                      + gb[4*q+2] * ab[4*q+2] * (da.z + f * (db.z - da.z))
                      + gb[4*q+3] * ab[4*q+3] * (da.w + f * (db.w - da.w));
            }
            dotb_buf[map_sr[i]] = dotb;    // random 4B; consumed by force_ra
        }
        dst_lds[tid] = dst;
        __syncthreads();

        int grp = tid >> 5;
        int c   = tid & 31;
        int b32 = grp * 32;
        int cur = -1; float run = 0.f;
        for (int k = 0; k < 32; k++) {
            int d = dst_lds[b32 + k];
            if (d != cur) {
                if (cur >= 0) unsafeAtomicAdd(&g1acc[(size_t)cur * 32 + c], run);
                cur = d;
                run = (d >= 0) ? m_lds[b32 + k][c] : 0.f;
            } else if (d >= 0) {
                run += m_lds[b32 + k][c];
            }
        }
        if (cur >= 0) unsafeAtomicAdd(&g1acc[(size_t)cur * 32 + c], run);
        __syncthreads();
    }
}

// force pass 1 (receiver-sorted): branch-a dot with INLINE g1 finalize.
__global__ __launch_bounds__(256) void k_force_ra(
    const float4* __restrict__ rec, const int* __restrict__ cnt,
    const float* __restrict__ dta,
    const unsigned short* __restrict__ hA1_bf,
    const float* __restrict__ g1acc, const float* __restrict__ g2,
    const float* __restrict__ Wr1, const float* __restrict__ dotb_buf,
    float* __restrict__ forces, float* __restrict__ sc_buf)
{
    __shared__ float f_lds[256][4];
    __shared__ int   dst_lds[256];

    int na = *cnt;
    int tid = threadIdx.x;
    int stride = gridDim.x * 256;
    const float4* w4 = (const float4*)Wr1;

    for (int base = blockIdx.x * 256; base < na; base += stride) {
        int i = base + tid;
        int dstf = -1;
        float fx = 0.f, fy = 0.f, fz = 0.f;

        if (i < na) {
            float4 rv = rec[i];
            unsigned pk = __float_as_uint(rv.w);
            int r = (int)(pk & 0xffffu);
            int s = (int)(pk >> 16);
            float vx = rv.x, vy = rv.y, vz = rv.z;
            float ss2 = vx * vx + vy * vy + vz * vz;
            float scv = 0.f;
            if (ss2 > 1e-12f) {          // else grad of maximum() is 0
                float L = sqrtf(ss2);
                float invL = 1.f / L;
                float x = fminf(L * (INV_R * (float)TBL), (float)TBL - 1e-3f);
                int   i0 = (int)x;
                float f  = x - (float)i0;

                float hb[32];
                load_bf_row(hA1_bf + (size_t)s * 64, hb);   // random 64B

                const float4* a0 = (const float4*)(dta + (size_t)i0 * 32);
                const float4* a1 = a0 + 8;
                const float4* pa = (const float4*)(g1acc + (size_t)r * 32);
                const float4* pc = (const float4*)(g2 + (size_t)r * 32);

                float dot = dotb_buf[i];                    // branch-b partial
#pragma unroll
                for (int q = 0; q < 8; q++) {
                    float4 ga = pa[q], gc = pc[q], wr = w4[q];
                    float4 t0 = a0[q], t1 = a1[q];
                    float g0 = ga.x * INV_AVG + gc.x + wr.x;  // inline node3
                    float g1v = ga.y * INV_AVG + gc.y + wr.y;
                    float g2v = ga.z * INV_AVG + gc.z + wr.z;
                    float g3 = ga.w * INV_AVG + gc.w + wr.w;
                    dot += g0 * hb[4*q+0] * (t0.x + f * (t1.x - t0.x))
                         + g1v * hb[4*q+1] * (t0.y + f * (t1.y - t0.y))
                         + g2v * hb[4*q+2] * (t0.z + f * (t1.z - t0.z))
                         + g3 * hb[4*q+3] * (t0.w + f * (t1.w - t0.w));
                }

                scv = INV_AVG * INV_R * dot * invL;        // dE/dL / L
                fx = -scv * vx; fy = -scv * vy; fz = -scv * vz;
                dstf = r;
            }
            sc_buf[i] = scv;             // coalesced; consumed by k_force_s2
        }
        f_lds[tid][0] = fx; f_lds[tid][1] = fy; f_lds[tid][2] = fz;
        dst_lds[tid] = dstf;
        __syncthreads();

        int grp = tid >> 5;
        int c   = tid & 31;
        if (c < 3) {
            int b32 = grp * 32;
            int cur = -1; float run = 0.f;
            for (int k = 0; k < 32; k++) {
                int d = dst_lds[b32 + k];
                if (d != cur) {
                    if (cur >= 0) unsafeAtomicAdd(&forces[3 * cur + c], run);
                    cur = d;
                    run = (d >= 0) ? f_lds[b32 + k][c] : 0.f;
                } else if (d >= 0) {
                    run += f_lds[b32 + k][c];
                }
            }
            if (cur >= 0) unsafeAtomicAdd(&forces[3 * cur + c], run);
        }
        __syncthreads();
    }
}

// force pass 2 (sender-sorted): cached scalar via srec->rrec map.
__global__ __launch_bounds__(256) void k_force_s2(
    const float4* __restrict__ rec, const int* __restrict__ cnt,
    const int* __restrict__ map_sr, const float* __restrict__ sc_buf,
    float* __restrict__ forces)
{
    __shared__ float f_lds[256][4];
    __shared__ int   dst_lds[256];

    int na = *cnt;
    int tid = threadIdx.x;
    int stride = gridDim.x * 256;

    for (int base = blockIdx.x * 256; base < na; base += stride) {
        int i = base + tid;
        int dstf = -1;
        float fx = 0.f, fy = 0.f, fz = 0.f;
        if (i < na) {
            float4 rv = rec[i];
            unsigned pk = __float_as_uint(rv.w);
            float scv = sc_buf[map_sr[i]];
            fx = scv * rv.x; fy = scv * rv.y; fz = scv * rv.z;
            dstf = (int)(pk & 0xffffu);   // own = sender
        }
        f_lds[tid][0] = fx; f_lds[tid][1] = fy; f_lds[tid][2] = fz;
        dst_lds[tid] = dstf;
        __syncthreads();

        int grp = tid >> 5;
        int c   = tid & 31;
        if (c < 3) {
            int b32 = grp * 32;
            int cur = -1; float run = 0.f;
            for (int k = 0; k < 32; k++) {
                int d = dst_lds[b32 + k];
                if (d != cur) {
                    if (cur >= 0) unsafeAtomicAdd(&forces[3 * cur + c], run);
                    cur = d;
                    run = (d >= 0) ? f_lds[b32 + k][c] : 0.f;
                } else if (d >= 0) {
                    run += f_lds[b32 + k][c];
                }
            }
            if (cur >= 0) unsafeAtomicAdd(&forces[3 * cur + c], run);
        }
        __syncthreads();
    }
}

extern "C" void kernel_launch(void* const* d_in, const int* in_sizes, int n_in,
                              void* d_out, int out_size, void* d_ws, size_t ws_size,
                              hipStream_t stream)
{
    const float* pos    = (const float*)d_in[0];
    const float* attrs  = (const float*)d_in[1];
    const float* shifts = (const float*)d_in[2];
    const float* ae     = (const float*)d_in[3];
    const float* Wemb   = (const float*)d_in[4];
    const float* W1a    = (const float*)d_in[5];
    const float* W2a    = (const float*)d_in[6];
    const float* Wr1    = (const float*)d_in[7];
    const float* W1b    = (const float*)d_in[8];
    const float* W2b    = (const float*)d_in[9];
    const float* Wm1    = (const float*)d_in[10];
    const float* Wm2    = (const float*)d_in[11];
    const int*   ei     = (const int*)d_in[12];
    const int*   batch  = (const int*)d_in[13];

    int N = in_sizes[13];
    int E = in_sizes[12] / 2;

    float* out    = (float*)d_out;
    float* total  = out;                 // 32
    float* node_e = out + 32;            // N
    float* forces = out + 32 + N;        // 3N

    float* ws = (float*)d_ws;
    size_t NC = (size_t)N * 32;
    float* h    = ws;            // N*32
    float* A1   = h  + NC;       // N*32
    float* A2g2 = A1 + NC;       // N*32 : A2 acc, then g2 in place
    float* g1   = A2g2 + NC;     // N*32 : acc (finalized inline in force_ra)
    float* e0   = g1 + NC;       // N
    float* e1   = e0 + N;        // N
    int* hist_r = (int*)(e1 + N);   // N
    int* hist_s = hist_r + N;       // N
    int* cur_r  = hist_s + N;       // N
    int* cur_s  = cur_r + N;        // N
    int* cnt    = cur_s + N;        // 1
    size_t ioff = ((size_t)(cnt + 1 - (int*)ws) + 3) & ~(size_t)3;
    float4* rrec = (float4*)(ws + ioff);   // E float4
    float4* srec = rrec + E;               // E float4
    float* tbl  = (float*)(srec + E);      // 4 tables of (TBL+1)*32
    size_t tstride = (size_t)(TBL + 1) * 32;
    float* twa = tbl;
    float* dta = twa + tstride;
    float* twb = dta + tstride;
    float* dtb = twb + tstride;
    int*   map_sr = (int*)(dtb + tstride);   // E
    float* sc_buf = (float*)(map_sr + E);    // E
    unsigned short* hA1_bf = (unsigned short*)(sc_buf + E);  // 2*NC ushorts
    unsigned short* g2_bf  = hA1_bf + 2 * NC;                // NC ushorts
    int* part  = (int*)(g2_bf + NC);                         // <=1024 ints
    int* bbase = part + 1024;                                // <=1024 ints
    float* dotb_buf = (float*)(bbase + 1024);                // E floats
    int*   rp_of_e  = (int*)(dotb_buf + E);                  // E ints
    // urec aliases A2g2+g1 (2*NC floats == E float4s when E == 16N)
    float4* urec = (float4*)A2g2;

    int nb_n  = (N + 255) / 256;
    int nb_e  = (E + 255) / 256;
    int nb_e2 = (E + 511) / 512;            // ILP-2 sort grids
    int nb_g  = nb_e < 2048 ? nb_e : 2048;  // grid-stride for edge passes
    int nb_t  = ((TBL + 1) * 16 + 255) / 256;
    int nbs   = (N + SCHUNK - 1) / SCHUNK;  // scan chunks per histogram

    // zero histograms BEFORE k_setup: zeroing them inside k_setup's embed
    // path raced with the build path's atomics (undefined block order).
    hipMemsetAsync(hist_r, 0, (size_t)N * 2 * sizeof(int), stream);

    k_setup<<<nb_t + nb_n + nb_e, 256, 0, stream>>>(
        W1a, W2a, W1b, W2b, twa, dta, twb, dtb, total,
        attrs, ae, Wemb, h, hA1_bf, e0, A1, forces, N,
        pos, shifts, ei, E, hist_r, hist_s, urec, nb_t, nb_n);
    k_scan_a<<<2 * nbs, 256, 0, stream>>>(hist_r, hist_s, N, nbs, part);
    k_scan_b<<<1, 256, 0, stream>>>(part, nbs, bbase, cnt);
    k_scan_c<<<2 * nbs, 256, 0, stream>>>(hist_r, hist_s, N, nbs, bbase,
                                          cur_r, cur_s);
    k_sort_r<<<nb_e2, 256, 0, stream>>>(urec, E, cur_r, rrec, rp_of_e);

    k_mlp1_sorts<<<nb_g + nb_e2, 256, 0, stream>>>(
        rrec, cnt, twa, hA1_bf, A1,
        urec, E, cur_s, srec, map_sr, rp_of_e, nb_g);
    k_node1<<<nb_n, 256, 0, stream>>>(h, A1, hA1_bf, Wr1, e1, A2g2, N);
    k_edge_mlp_t<<<nb_g, 256, 0, stream>>>(rrec, cnt, twb, hA1_bf + 32, 64, A2g2);
    k_node2<<<nb_n, 256, 0, stream>>>(A2g2, g2_bf, A1, Wm1, Wm2, e0, e1,
                                      node_e, total, g1, batch, N);
    k_mlp3fb<<<nb_g, 256, 0, stream>>>(srec, cnt, twb, dtb, g2_bf, hA1_bf,
                                       map_sr, g1, dotb_buf);
    k_force_ra<<<nb_g, 256, 0, stream>>>(rrec, cnt, dta, hA1_bf,
                                         g1, A2g2, Wr1, dotb_buf,
                                         forces, sc_buf);
    k_force_s2<<<nb_g, 256, 0, stream>>>(srec, cnt, map_sr, sc_buf, forces);
}